// Round 25
// baseline (139.351 us; speedup 1.0000x reference)
//
#include <hip/hip_runtime.h>
#include <hip/hip_bf16.h>

#define N_ROWS 8192
#define DIM    1024
#define NCLS   10240
#define S_SCALE 30.0f
#define M_LARGE 0.4f
#define M_SMALL 0.1f

typedef __attribute__((ext_vector_type(4))) int   i32x4;

#define GLD16(gp, lp) __builtin_amdgcn_global_load_lds( \
    (const __attribute__((address_space(1))) unsigned int*)(gp), \
    (__attribute__((address_space(3))) unsigned int*)(lp), 16, 0, 0)

// ---- prep: per-row symmetric int8 quantization + combined scale, zero gsum ----
__global__ void prep_kernel(const float* __restrict__ x, const float* __restrict__ w,
                            float* __restrict__ fx, float* __restrict__ fw,
                            float* __restrict__ gsum,
                            signed char* __restrict__ xq, signed char* __restrict__ wq){
    int b = blockIdx.x;
    bool isx = (b < N_ROWS);
    int r = isx ? b : b - N_ROWS;
    const float4* src = (const float4*)((isx ? x : w) + (size_t)r * DIM);
    float4 v = src[threadIdx.x];                      // 256 threads * 4 = 1024
    float ss = v.x*v.x + v.y*v.y + v.z*v.z + v.w*v.w;
    float am = fmaxf(fmaxf(fabsf(v.x), fabsf(v.y)), fmaxf(fabsf(v.z), fabsf(v.w)));
    #pragma unroll
    for (int o = 32; o; o >>= 1){
        ss += __shfl_down(ss, o);
        am  = fmaxf(am, __shfl_down(am, o));
    }
    __shared__ float pss[4], pam[4];
    int lane = threadIdx.x & 63, wid = threadIdx.x >> 6;
    if (lane == 0){ pss[wid] = ss; pam[wid] = am; }
    __syncthreads();
    float t    = pss[0] + pss[1] + pss[2] + pss[3];
    float amax = fmaxf(fmaxf(pam[0], pam[1]), fmaxf(pam[2], pam[3]));
    float inv  = 1.0f / fmaxf(sqrtf(t), 1e-12f);
    float s    = fmaxf(amax, 1e-20f) * (1.0f/127.0f);
    float rs   = 127.0f / fmaxf(amax, 1e-20f);
    int q0 = __float2int_rn(v.x * rs), q1 = __float2int_rn(v.y * rs);
    int q2 = __float2int_rn(v.z * rs), q3 = __float2int_rn(v.w * rs);
    unsigned int pk = (q0 & 0xff) | ((q1 & 0xff) << 8) | ((q2 & 0xff) << 16) | ((q3 & 0xff) << 24);
    ((unsigned int*)((isx ? xq : wq) + (size_t)r * DIM))[threadIdx.x] = pk;
    if (threadIdx.x == 0){
        if (isx){ fx[r] = s * inv; gsum[r] = 0.0f; }
        else      fw[r] = s * inv;
    }
}

// ---- fused i8 GEMM: persistent blocks (256), each 5 output tiles of 256x256,
// 16 waves, double-buffered LDS, cross-tile staging pipeline, fused target ----
#define BM 256
#define BN 256
#define BKB 128              // i8 bytes per K-tile
#define NT (DIM/BKB)         // 8
#define GRID_X (NCLS/BN)     // 40
#define GRID_Y (N_ROWS/BM)   // 32
#define NWG (GRID_X*GRID_Y)  // 1280 output tiles
#define NBLK 256             // persistent blocks; 5 tiles each
#define TPB (NWG/NBLK)       // 5

__global__ __launch_bounds__(1024) void gemm_kernel(
        const signed char* __restrict__ xq, const signed char* __restrict__ wq,
        const float* __restrict__ fx, const float* __restrict__ fw,
        const int* __restrict__ labels,
        float* __restrict__ gsum, float* __restrict__ tgt){
    __shared__ __align__(16) unsigned char As[2][BM*BKB];   // 2 x 32 KB
    __shared__ __align__(16) unsigned char Bs[2][BN*BKB];   // 2 x 32 KB
    __shared__ float sumrow[BM];
    __shared__ int   lab_s[BM];

    int tid = threadIdx.x;
    int bid = blockIdx.x;
    int wid = tid >> 6, lane = tid & 63;
    int wm = wid >> 2, wn = wid & 3;           // 4x4 waves; wave owns 64x64
    int g = lane >> 4, l16 = lane & 15;

    // staging geometry: one GLD16 = 1024 thr x 16B = 128 rows x 128 B
    int srow = tid >> 3;                       // 0..127
    int csrc = (tid & 7) ^ (srow & 7);         // pre-swizzled source chunk
    int ldso = srow * BKB + (tid & 7) * 16;    // linear LDS dest (bytes)

    // bijective tile assignment: swz = (bid&7)*160 + (bid>>3) + 32*t
    #define TILEBASE(T, R, C) { int swz_ = (bid & 7)*(NWG/8) + (bid >> 3) + 32*(T); \
                                R = (swz_ / GRID_X) * BM; C = (swz_ % GRID_X) * BN; }

    int row0, col0;
    TILEBASE(0, row0, col0);
    const signed char* gA = xq + (size_t)(row0 + srow) * DIM + csrc * 16;
    const signed char* gB = wq + (size_t)(col0 + srow) * DIM + csrc * 16;

    // prologue: stage tile0 k0
    GLD16(gA,                   &As[0][ldso]);
    GLD16(gA + (size_t)128*DIM, &As[0][128*BKB + ldso]);
    GLD16(gB,                   &Bs[0][ldso]);
    GLD16(gB + (size_t)128*DIM, &Bs[0][128*BKB + ldso]);
    if (tid < BM){ sumrow[tid] = 0.f; lab_s[tid] = labels[row0 + tid]; }
    __syncthreads();                            // drains vmcnt

    for (int t = 0; t < TPB; ++t){
        int nrow0 = 0, ncol0 = 0;
        const signed char* ngA = gA;
        const signed char* ngB = gB;
        if (t + 1 < TPB){
            TILEBASE(t + 1, nrow0, ncol0);
            ngA = xq + (size_t)(nrow0 + srow) * DIM + csrc * 16;
            ngB = wq + (size_t)(ncol0 + srow) * DIM + csrc * 16;
        }

        i32x4 acc[4][4] = {};

        for (int kt = 0; kt < NT; ++kt){
            int b = kt & 1, nb = b ^ 1;
            if (kt + 1 < NT){
                int kn = (kt + 1) * BKB;
                GLD16(gA + kn,                   &As[nb][ldso]);
                GLD16(gA + kn + (size_t)128*DIM, &As[nb][128*BKB + ldso]);
                GLD16(gB + kn,                   &Bs[nb][ldso]);
                GLD16(gB + kn + (size_t)128*DIM, &Bs[nb][128*BKB + ldso]);
            } else if (t + 1 < TPB){
                // stage NEXT OUTPUT TILE's k0 — drained after the epilogue
                GLD16(ngA,                   &As[nb][ldso]);
                GLD16(ngA + (size_t)128*DIM, &As[nb][128*BKB + ldso]);
                GLD16(ngB,                   &Bs[nb][ldso]);
                GLD16(ngB + (size_t)128*DIM, &Bs[nb][128*BKB + ldso]);
            }

            #pragma unroll
            for (int kk = 0; kk < 2; ++kk){
                i32x4 af[4], bfv[4];
                #pragma unroll
                for (int m = 0; m < 4; ++m){
                    int r = wm*64 + m*16 + l16;
                    af[m] = *(const i32x4*)&As[b][r*BKB + (((kk*4+g) ^ (r & 7)) << 4)];
                }
                #pragma unroll
                for (int n = 0; n < 4; ++n){
                    int r = wn*64 + n*16 + l16;
                    bfv[n] = *(const i32x4*)&Bs[b][r*BKB + (((kk*4+g) ^ (r & 7)) << 4)];
                }
                #pragma unroll
                for (int m = 0; m < 4; ++m)
                    #pragma unroll
                    for (int n = 0; n < 4; ++n)
                        acc[m][n] = __builtin_amdgcn_mfma_i32_16x16x64_i8(af[m], bfv[n], acc[m][n], 0, 0, 0);
            }

            if (kt + 1 < NT){
                asm volatile("s_waitcnt vmcnt(0)" ::: "memory");
                __syncthreads();
            }
            // last K-step: fall into epilogue, staged loads stay in flight
        }

        // epilogue: cosine = acc*fx*fw; clamp; exp-sum; target extraction
        float fwv[4];
        #pragma unroll
        for (int n = 0; n < 4; ++n) fwv[n] = fw[col0 + wn*64 + n*16 + l16];
        #pragma unroll
        for (int m = 0; m < 4; ++m){
            #pragma unroll
            for (int rg = 0; rg < 4; ++rg){
                int rl = wm*64 + m*16 + g*4 + rg;
                float fxr = fx[row0 + rl];
                int lab = lab_s[rl];
                float v = 0.f;
                #pragma unroll
                for (int n = 0; n < 4; ++n){
                    float c = (float)acc[m][n][rg] * fxr * fwv[n];
                    c = fminf(fmaxf(c, -1.f), 1.f);
                    v += __expf(S_SCALE * c);
                    if (lab == col0 + wn*64 + n*16 + l16) tgt[row0 + rl] = c;
                }
                v += __shfl_xor(v, 1);
                v += __shfl_xor(v, 2);
                v += __shfl_xor(v, 4);
                v += __shfl_xor(v, 8);
                if (l16 == 0) atomicAdd(&sumrow[rl], v);
            }
        }
        __syncthreads();
        if (tid < BM) atomicAdd(&gsum[row0 + tid], sumrow[tid]);

        if (t + 1 < TPB){
            row0 = nrow0; col0 = ncol0; gA = ngA; gB = ngB;
            // staged k0 loads are now epilogue-duration old: drain ~free
            asm volatile("s_waitcnt vmcnt(0)" ::: "memory");
            __syncthreads();
            if (tid < BM){ sumrow[tid] = 0.f; lab_s[tid] = labels[row0 + tid]; }
            __syncthreads();
        }
    }
}

// ---------------- finalize: per-row loss, mean (1024 threads) ----------------
__global__ void finalize_kernel(const float* __restrict__ tgt, const float* __restrict__ gsum,
                                const int* __restrict__ labels, float* __restrict__ out){
    double local = 0.0;
    for (int i = threadIdx.x; i < N_ROWS; i += 1024){
        float tv = tgt[i];
        float m  = (labels[i] <= 5) ? M_LARGE : M_SMALL;
        float numer = S_SCALE * (tv - m);
        float excl  = gsum[i] - __expf(S_SCALE * tv);
        float denom = __expf(numer) + excl;
        float L = numer - logf(denom);
        local += (double)L;
    }
    #pragma unroll
    for (int o = 32; o; o >>= 1) local += __shfl_down(local, o);
    __shared__ double part[16];
    int lane = threadIdx.x & 63, wid = threadIdx.x >> 6;
    if (lane == 0) part[wid] = local;
    __syncthreads();
    if (threadIdx.x == 0){
        double s = 0.0;
        #pragma unroll
        for (int p = 0; p < 16; ++p) s += part[p];
        out[0] = (float)(-s / (double)N_ROWS);
    }
}

extern "C" void kernel_launch(void* const* d_in, const int* in_sizes, int n_in,
                              void* d_out, int out_size, void* d_ws, size_t ws_size,
                              hipStream_t stream) {
    const float* x      = (const float*)d_in[0];
    const int*   labels = (const int*)  d_in[1];
    const float* w      = (const float*)d_in[2];

    float* ws    = (float*)d_ws;
    float* fx    = ws;                    // N
    float* fw    = fx    + N_ROWS;        // C
    float* tgt   = fw    + NCLS;          // N
    float* gsum  = tgt   + N_ROWS;        // N
    signed char* xq = (signed char*)(gsum + N_ROWS);   // N*D i8
    signed char* wq = xq + (size_t)N_ROWS * DIM;       // C*D i8

    prep_kernel<<<N_ROWS + NCLS, 256, 0, stream>>>(x, w, fx, fw, gsum, xq, wq);
    gemm_kernel<<<NBLK, 1024, 0, stream>>>(xq, wq, fx, fw, labels, gsum, tgt);
    finalize_kernel<<<1, 1024, 0, stream>>>(tgt, gsum, labels, (float*)d_out);
}

// Round 26
// 132.870 us; speedup vs baseline: 1.0488x; 1.0488x over previous
//
#include <hip/hip_runtime.h>
#include <hip/hip_bf16.h>

#define N_ROWS 8192
#define DIM    1024
#define NCLS   10240
#define S_SCALE 30.0f
#define M_LARGE 0.4f
#define M_SMALL 0.1f

typedef __attribute__((ext_vector_type(4))) int   i32x4;

#define GLD16(gp, lp) __builtin_amdgcn_global_load_lds( \
    (const __attribute__((address_space(1))) unsigned int*)(gp), \
    (__attribute__((address_space(3))) unsigned int*)(lp), 16, 0, 0)

// ---- prep: per-row symmetric int8 quantization + combined scale, zero gsum ----
__global__ void prep_kernel(const float* __restrict__ x, const float* __restrict__ w,
                            float* __restrict__ fx, float* __restrict__ fw,
                            float* __restrict__ gsum,
                            signed char* __restrict__ xq, signed char* __restrict__ wq){
    int b = blockIdx.x;
    bool isx = (b < N_ROWS);
    int r = isx ? b : b - N_ROWS;
    const float4* src = (const float4*)((isx ? x : w) + (size_t)r * DIM);
    float4 v = src[threadIdx.x];                      // 256 threads * 4 = 1024
    float ss = v.x*v.x + v.y*v.y + v.z*v.z + v.w*v.w;
    float am = fmaxf(fmaxf(fabsf(v.x), fabsf(v.y)), fmaxf(fabsf(v.z), fabsf(v.w)));
    #pragma unroll
    for (int o = 32; o; o >>= 1){
        ss += __shfl_down(ss, o);
        am  = fmaxf(am, __shfl_down(am, o));
    }
    __shared__ float pss[4], pam[4];
    int lane = threadIdx.x & 63, wid = threadIdx.x >> 6;
    if (lane == 0){ pss[wid] = ss; pam[wid] = am; }
    __syncthreads();
    float t    = pss[0] + pss[1] + pss[2] + pss[3];
    float amax = fmaxf(fmaxf(pam[0], pam[1]), fmaxf(pam[2], pam[3]));
    float inv  = 1.0f / fmaxf(sqrtf(t), 1e-12f);
    float s    = fmaxf(amax, 1e-20f) * (1.0f/127.0f);
    float rs   = 127.0f / fmaxf(amax, 1e-20f);
    int q0 = __float2int_rn(v.x * rs), q1 = __float2int_rn(v.y * rs);
    int q2 = __float2int_rn(v.z * rs), q3 = __float2int_rn(v.w * rs);
    unsigned int pk = (q0 & 0xff) | ((q1 & 0xff) << 8) | ((q2 & 0xff) << 16) | ((q3 & 0xff) << 24);
    ((unsigned int*)((isx ? xq : wq) + (size_t)r * DIM))[threadIdx.x] = pk;
    if (threadIdx.x == 0){
        if (isx){ fx[r] = s * inv; gsum[r] = 0.0f; }
        else      fw[r] = s * inv;
    }
}

// ---- fused i8 GEMM: 256x256 tile, K-tile=128 i8, 16 waves (4Mx4N, 64x64/wave),
// double-buffered LDS, one barrier per tile; fused target extraction ----
#define BM 256
#define BN 256
#define BKB 128              // i8 bytes per K-tile
#define NT (DIM/BKB)         // 8
#define GRID_X (NCLS/BN)     // 40
#define GRID_Y (N_ROWS/BM)   // 32
#define NWG (GRID_X*GRID_Y)  // 1280, % 8 == 0

__global__ __launch_bounds__(1024) void gemm_kernel(
        const signed char* __restrict__ xq, const signed char* __restrict__ wq,
        const float* __restrict__ fx, const float* __restrict__ fw,
        const int* __restrict__ labels,
        float* __restrict__ gsum, float* __restrict__ tgt){
    __shared__ __align__(16) unsigned char As[2][BM*BKB];   // 2 x 32 KB
    __shared__ __align__(16) unsigned char Bs[2][BN*BKB];   // 2 x 32 KB
    __shared__ float sumrow[BM];
    __shared__ int   lab_s[BM];

    int tid = threadIdx.x;
    int bid = blockIdx.x;
    // bijective XCD swizzle
    int swz = (bid & 7) * (NWG/8) + (bid >> 3);
    int by = swz / GRID_X, bx = swz % GRID_X;
    int row0 = by * BM, col0 = bx * BN;
    int wid = tid >> 6, lane = tid & 63;
    int wm = wid >> 2, wn = wid & 3;           // 4x4 waves; wave owns 64x64
    int g = lane >> 4, l16 = lane & 15;

    if (tid < BM){ sumrow[tid] = 0.f; lab_s[tid] = labels[row0 + tid]; }

    // staging geometry: one GLD16 = 1024 thr x 16B = 128 rows x 128 B
    int srow = tid >> 3;                       // 0..127
    int csrc = (tid & 7) ^ (srow & 7);         // pre-swizzled source chunk (16B units)
    const signed char* gA = xq + (size_t)(row0 + srow) * DIM + csrc * 16;
    const signed char* gB = wq + (size_t)(col0 + srow) * DIM + csrc * 16;
    int ldso = srow * BKB + (tid & 7) * 16;    // linear LDS dest (bytes)

    i32x4 acc[4][4] = {};

    // prologue: stage tile 0 (2 GLD16 per operand)
    GLD16(gA,                     &As[0][ldso]);
    GLD16(gA + (size_t)128*DIM,   &As[0][128*BKB + ldso]);
    GLD16(gB,                     &Bs[0][ldso]);
    GLD16(gB + (size_t)128*DIM,   &Bs[0][128*BKB + ldso]);
    __syncthreads();                            // compiler drains vmcnt

    for (int kt = 0; kt < NT; ++kt){
        int b = kt & 1, nb = b ^ 1;
        if (kt + 1 < NT){
            int kn = (kt + 1) * BKB;
            GLD16(gA + kn,                     &As[nb][ldso]);
            GLD16(gA + kn + (size_t)128*DIM,   &As[nb][128*BKB + ldso]);
            GLD16(gB + kn,                     &Bs[nb][ldso]);
            GLD16(gB + kn + (size_t)128*DIM,   &Bs[nb][128*BKB + ldso]);
        }

        // fragments: lane (g,l16) reads 16B chunks (kk*4+g)^(r&7), kk in {0,1}
        #pragma unroll
        for (int kk = 0; kk < 2; ++kk){
            i32x4 af[4], bfv[4];
            #pragma unroll
            for (int m = 0; m < 4; ++m){
                int r = wm*64 + m*16 + l16;
                af[m] = *(const i32x4*)&As[b][r*BKB + (((kk*4+g) ^ (r & 7)) << 4)];
            }
            #pragma unroll
            for (int n = 0; n < 4; ++n){
                int r = wn*64 + n*16 + l16;
                bfv[n] = *(const i32x4*)&Bs[b][r*BKB + (((kk*4+g) ^ (r & 7)) << 4)];
            }
            #pragma unroll
            for (int m = 0; m < 4; ++m)
                #pragma unroll
                for (int n = 0; n < 4; ++n)
                    acc[m][n] = __builtin_amdgcn_mfma_i32_16x16x64_i8(af[m], bfv[n], acc[m][n], 0, 0, 0);
        }

        // one drain + one barrier per tile
        asm volatile("s_waitcnt vmcnt(0)" ::: "memory");
        __syncthreads();
    }

    // epilogue: cosine = acc * fx[i] * fw[j]; clamp; exp-sum; target extraction
    // C/D layout: col = lane&15 (+n*16+wn*64), row = g*4+rg (+m*16+wm*64)
    float fwv[4];
    #pragma unroll
    for (int n = 0; n < 4; ++n) fwv[n] = fw[col0 + wn*64 + n*16 + l16];
    #pragma unroll
    for (int m = 0; m < 4; ++m){
        #pragma unroll
        for (int rg = 0; rg < 4; ++rg){
            int rl = wm*64 + m*16 + g*4 + rg;        // local row
            float fxr = fx[row0 + rl];
            int lab = lab_s[rl];
            float v = 0.f;
            #pragma unroll
            for (int n = 0; n < 4; ++n){
                float c = (float)acc[m][n][rg] * fxr * fwv[n];
                c = fminf(fmaxf(c, -1.f), 1.f);
                v += __expf(S_SCALE * c);
                if (lab == col0 + wn*64 + n*16 + l16) tgt[row0 + rl] = c;
            }
            v += __shfl_xor(v, 1);
            v += __shfl_xor(v, 2);
            v += __shfl_xor(v, 4);
            v += __shfl_xor(v, 8);
            if (l16 == 0) atomicAdd(&sumrow[rl], v);
        }
    }
    __syncthreads();
    if (tid < BM) atomicAdd(&gsum[row0 + tid], sumrow[tid]);
}

// ---------------- finalize: per-row loss, mean (1024 threads) ----------------
__global__ void finalize_kernel(const float* __restrict__ tgt, const float* __restrict__ gsum,
                                const int* __restrict__ labels, float* __restrict__ out){
    double local = 0.0;
    for (int i = threadIdx.x; i < N_ROWS; i += 1024){
        float tv = tgt[i];
        float m  = (labels[i] <= 5) ? M_LARGE : M_SMALL;
        float numer = S_SCALE * (tv - m);
        float excl  = gsum[i] - __expf(S_SCALE * tv);
        float denom = __expf(numer) + excl;
        float L = numer - logf(denom);
        local += (double)L;
    }
    #pragma unroll
    for (int o = 32; o; o >>= 1) local += __shfl_down(local, o);
    __shared__ double part[16];
    int lane = threadIdx.x & 63, wid = threadIdx.x >> 6;
    if (lane == 0) part[wid] = local;
    __syncthreads();
    if (threadIdx.x == 0){
        double s = 0.0;
        #pragma unroll
        for (int p = 0; p < 16; ++p) s += part[p];
        out[0] = (float)(-s / (double)N_ROWS);
    }
}

extern "C" void kernel_launch(void* const* d_in, const int* in_sizes, int n_in,
                              void* d_out, int out_size, void* d_ws, size_t ws_size,
                              hipStream_t stream) {
    const float* x      = (const float*)d_in[0];
    const int*   labels = (const int*)  d_in[1];
    const float* w      = (const float*)d_in[2];

    float* ws    = (float*)d_ws;
    float* fx    = ws;                    // N
    float* fw    = fx    + N_ROWS;        // C
    float* tgt   = fw    + NCLS;          // N
    float* gsum  = tgt   + N_ROWS;        // N
    signed char* xq = (signed char*)(gsum + N_ROWS);   // N*D i8
    signed char* wq = xq + (size_t)N_ROWS * DIM;       // C*D i8

    prep_kernel<<<N_ROWS + NCLS, 256, 0, stream>>>(x, w, fx, fw, gsum, xq, wq);
    gemm_kernel<<<NWG, 1024, 0, stream>>>(xq, wq, fx, fw, labels, gsum, tgt);
    finalize_kernel<<<1, 1024, 0, stream>>>(tgt, gsum, labels, (float*)d_out);
}